// Round 11
// baseline (244.692 us; speedup 1.0000x reference)
//
#include <hip/hip_runtime.h>

#define NCACHE 384

__device__ __forceinline__ unsigned int sortable_bits(float f) {
    unsigned int u = __float_as_uint(f);
    return (u & 0x80000000u) ? ~u : (u | 0x80000000u);
}

// 256 threads = 4 waves; wave w handles b = blockIdx.x*4 + w entirely.
// Lane owns keys m0=lane (chunk 0) and m1=64+lane (chunk 1).
// Stable rank r(m) = #{j in higher chunks: v_j < v_m}
//                  + #{j in lower  chunks: v_j <= v_m}
//                  + #{j in own chunk: v_j < v_m  or (v_j == v_m and j < m)}
// Rank loop reads each uint4 of vals exactly ONCE (96 ds_read_b128/wave —
// the LDS-pipe floor; DS throughput is the measured wall, R4-R10).
__global__ __launch_bounds__(256) void fused_kernel(
    const float*  __restrict__ cache,        // (384,5)
    const float*  __restrict__ refdirs,      // (B,3)
    const float*  __restrict__ normal,       // (B,3)
    const float4* __restrict__ samp_rays4,   // B*96 float4
    const float4* __restrict__ samp_mip4,    // B*32 float4
    float* __restrict__ out, int B)
{
#pragma clang fp contract(off)
    __shared__ __align__(16) float4 scache[NCACHE];         // dir.xyz, mip
    __shared__ __align__(16) unsigned int vals[4][NCACHE];  // per-wave sortable words
    __shared__ unsigned int bitmap[4][12];

    const int tid  = threadIdx.x;
    const int wave = tid >> 6;
    const int lane = tid & 63;
    const int b    = blockIdx.x * 4 + wave;

    // Early-issue pass-through copy loads (hide HBM under the rank loop).
    const int b0 = blockIdx.x * 4;
    const int i0 = tid, i1 = tid + 256;
    const int bb0 = b0 + (i0 >> 7), off0 = i0 & 127;
    const int bb1 = b0 + (i1 >> 7), off1 = i1 & 127;
    const float4 c0 = (off0 < 96) ? samp_rays4[(size_t)bb0 * 96 + off0]
                                  : samp_mip4[(size_t)bb0 * 32 + (off0 - 96)];
    const float4 c1 = (off1 < 96) ? samp_rays4[(size_t)bb1 * 96 + off1]
                                  : samp_mip4[(size_t)bb1 * 32 + (off1 - 96)];

    // Stage cache into LDS as float4 (cooperative, once per block)
    for (int m = tid; m < NCACHE; m += 256) {
        scache[m] = make_float4(cache[m * 5 + 0], cache[m * 5 + 1],
                                cache[m * 5 + 2], cache[m * 5 + 3]);
    }
    if (tid < 48) (&bitmap[0][0])[tid] = 0u;

    const float nx = normal[b * 3 + 0], ny = normal[b * 3 + 1], nz = normal[b * 3 + 2];
    const float rx = refdirs[b * 3 + 0], ry = refdirs[b * 3 + 1], rz = refdirs[b * 3 + 2];

    __syncthreads();

    // Scores -> sortable value words (FMA left-chains, bit-exact vs reference;
    // -0.0 canonicalized to +0.0 so ties match float == semantics).
    unsigned int vk0 = 0, vk1 = 0;
#pragma unroll
    for (int c = 0; c < 6; ++c) {
        const int m = c * 64 + lane;
        const float4 d = scache[m];
        float hemi = __builtin_fmaf(nz, d.z, __builtin_fmaf(ny, d.y, nx * d.x));
        float sim  = __builtin_fmaf(rz, d.z, __builtin_fmaf(ry, d.y, rx * d.x));
        float val  = (hemi > 0.0f) ? -sim : 0.0f;
        val = val + 0.0f;
        const unsigned int sv = sortable_bits(val);
        vals[wave][m] = sv;
        if (c == 0) vk0 = sv;
        if (c == 1) vk1 = sv;
    }
    // Same-wave LDS write->read: DS pipe is in-order per wave (proven R8-R10);
    // no block barrier needed for per-wave arrays.

    const uint4* v4 = (const uint4*)&vals[wave][0];
    const unsigned int ulane = (unsigned int)lane;
    unsigned int r0 = 0, r1 = 0;
    unsigned long long sc;

    // Chunk 0 (i=0..15): own chunk of key0 (lt + tie), below key1 (le).
#pragma unroll 4
    for (int i = 0; i < 16; ++i) {
        const uint4 q = v4[i];
        asm("v_cmp_lt_u32 vcc, %[a], %[k0]\n\t"
            "v_cmp_le_u32 %[sc], %[a], %[k1]\n\t"
            "v_addc_co_u32 %[r0], vcc, 0, %[r0], vcc\n\t"
            "v_addc_co_u32 %[r1], %[sc], 0, %[r1], %[sc]\n\t"
            "v_cmp_lt_u32 vcc, %[b], %[k0]\n\t"
            "v_cmp_le_u32 %[sc], %[b], %[k1]\n\t"
            "v_addc_co_u32 %[r0], vcc, 0, %[r0], vcc\n\t"
            "v_addc_co_u32 %[r1], %[sc], 0, %[r1], %[sc]\n\t"
            "v_cmp_lt_u32 vcc, %[c], %[k0]\n\t"
            "v_cmp_le_u32 %[sc], %[c], %[k1]\n\t"
            "v_addc_co_u32 %[r0], vcc, 0, %[r0], vcc\n\t"
            "v_addc_co_u32 %[r1], %[sc], 0, %[r1], %[sc]\n\t"
            "v_cmp_lt_u32 vcc, %[d], %[k0]\n\t"
            "v_cmp_le_u32 %[sc], %[d], %[k1]\n\t"
            "v_addc_co_u32 %[r0], vcc, 0, %[r0], vcc\n\t"
            "v_addc_co_u32 %[r1], %[sc], 0, %[r1], %[sc]"
            : [r0]"+v"(r0), [r1]"+v"(r1), [sc]"=&s"(sc)
            : [a]"v"(q.x), [b]"v"(q.y), [c]"v"(q.z), [d]"v"(q.w),
              [k0]"v"(vk0), [k1]"v"(vk1)
            : "vcc");
        const unsigned int jb = (unsigned int)(i * 4);
        r0 += (unsigned int)((q.x == vk0) & (jb + 0u < ulane));
        r0 += (unsigned int)((q.y == vk0) & (jb + 1u < ulane));
        r0 += (unsigned int)((q.z == vk0) & (jb + 2u < ulane));
        r0 += (unsigned int)((q.w == vk0) & (jb + 3u < ulane));
    }

    // Chunk 1 (i=16..31): above key0 (lt), own chunk of key1 (lt + tie).
#pragma unroll 4
    for (int i = 16; i < 32; ++i) {
        const uint4 q = v4[i];
        asm("v_cmp_lt_u32 vcc, %[a], %[k0]\n\t"
            "v_cmp_lt_u32 %[sc], %[a], %[k1]\n\t"
            "v_addc_co_u32 %[r0], vcc, 0, %[r0], vcc\n\t"
            "v_addc_co_u32 %[r1], %[sc], 0, %[r1], %[sc]\n\t"
            "v_cmp_lt_u32 vcc, %[b], %[k0]\n\t"
            "v_cmp_lt_u32 %[sc], %[b], %[k1]\n\t"
            "v_addc_co_u32 %[r0], vcc, 0, %[r0], vcc\n\t"
            "v_addc_co_u32 %[r1], %[sc], 0, %[r1], %[sc]\n\t"
            "v_cmp_lt_u32 vcc, %[c], %[k0]\n\t"
            "v_cmp_lt_u32 %[sc], %[c], %[k1]\n\t"
            "v_addc_co_u32 %[r0], vcc, 0, %[r0], vcc\n\t"
            "v_addc_co_u32 %[r1], %[sc], 0, %[r1], %[sc]\n\t"
            "v_cmp_lt_u32 vcc, %[d], %[k0]\n\t"
            "v_cmp_lt_u32 %[sc], %[d], %[k1]\n\t"
            "v_addc_co_u32 %[r0], vcc, 0, %[r0], vcc\n\t"
            "v_addc_co_u32 %[r1], %[sc], 0, %[r1], %[sc]"
            : [r0]"+v"(r0), [r1]"+v"(r1), [sc]"=&s"(sc)
            : [a]"v"(q.x), [b]"v"(q.y), [c]"v"(q.z), [d]"v"(q.w),
              [k0]"v"(vk0), [k1]"v"(vk1)
            : "vcc");
        const unsigned int jb = (unsigned int)(i * 4 - 64);
        r1 += (unsigned int)((q.x == vk1) & (jb + 0u < ulane));
        r1 += (unsigned int)((q.y == vk1) & (jb + 1u < ulane));
        r1 += (unsigned int)((q.z == vk1) & (jb + 2u < ulane));
        r1 += (unsigned int)((q.w == vk1) & (jb + 3u < ulane));
    }

    // Chunks 2..5 (i=32..95): above both keys (lt, lt).
#pragma unroll 8
    for (int i = 32; i < 96; ++i) {
        const uint4 q = v4[i];
        asm("v_cmp_lt_u32 vcc, %[a], %[k0]\n\t"
            "v_cmp_lt_u32 %[sc], %[a], %[k1]\n\t"
            "v_addc_co_u32 %[r0], vcc, 0, %[r0], vcc\n\t"
            "v_addc_co_u32 %[r1], %[sc], 0, %[r1], %[sc]\n\t"
            "v_cmp_lt_u32 vcc, %[b], %[k0]\n\t"
            "v_cmp_lt_u32 %[sc], %[b], %[k1]\n\t"
            "v_addc_co_u32 %[r0], vcc, 0, %[r0], vcc\n\t"
            "v_addc_co_u32 %[r1], %[sc], 0, %[r1], %[sc]\n\t"
            "v_cmp_lt_u32 vcc, %[c], %[k0]\n\t"
            "v_cmp_lt_u32 %[sc], %[c], %[k1]\n\t"
            "v_addc_co_u32 %[r0], vcc, 0, %[r0], vcc\n\t"
            "v_addc_co_u32 %[r1], %[sc], 0, %[r1], %[sc]\n\t"
            "v_cmp_lt_u32 vcc, %[d], %[k0]\n\t"
            "v_cmp_lt_u32 %[sc], %[d], %[k1]\n\t"
            "v_addc_co_u32 %[r0], vcc, 0, %[r0], vcc\n\t"
            "v_addc_co_u32 %[r1], %[sc], 0, %[r1], %[sc]"
            : [r0]"+v"(r0), [r1]"+v"(r1), [sc]"=&s"(sc)
            : [a]"v"(q.x), [b]"v"(q.y), [c]"v"(q.z), [d]"v"(q.w),
              [k0]"v"(vk0), [k1]"v"(vk1)
            : "vcc");
    }

    // Ranks are distinct in [0,384). Output slot = #{selected ranks < r}.
    atomicOr(&bitmap[wave][r0 >> 5], 1u << (r0 & 31));
    atomicOr(&bitmap[wave][r1 >> 5], 1u << (r1 & 31));

    float* out_rays = out;
    float* out_mip  = out + (size_t)B * 768;

    {
        const int wi = (int)r0 >> 5;
        int s = __popc(bitmap[wave][wi] & ((1u << (r0 & 31)) - 1u));
        for (int w = 0; w < wi; ++w) s += __popc(bitmap[wave][w]);
        const float4 g = scache[r0];
        const size_t rb = (size_t)b * 768 + 384 + (size_t)s * 3;
        out_rays[rb + 0] = g.x;
        out_rays[rb + 1] = g.y;
        out_rays[rb + 2] = g.z;
        out_mip[(size_t)b * 256 + 128 + s] = g.w;
    }
    {
        const int wi = (int)r1 >> 5;
        int s = __popc(bitmap[wave][wi] & ((1u << (r1 & 31)) - 1u));
        for (int w = 0; w < wi; ++w) s += __popc(bitmap[wave][w]);
        const float4 g = scache[r1];
        const size_t rb = (size_t)b * 768 + 384 + (size_t)s * 3;
        out_rays[rb + 0] = g.x;
        out_rays[rb + 1] = g.y;
        out_rays[rb + 2] = g.z;
        out_mip[(size_t)b * 256 + 128 + s] = g.w;
    }

    // Pass-through copy stores (loads issued at kernel entry).
    float4* out4     = (float4*)out;
    float4* out_mip4 = (float4*)(out + (size_t)B * 768);
    if (off0 < 96) out4[(size_t)bb0 * 192 + off0] = c0;
    else           out_mip4[(size_t)bb0 * 64 + (off0 - 96)] = c0;
    if (off1 < 96) out4[(size_t)bb1 * 192 + off1] = c1;
    else           out_mip4[(size_t)bb1 * 64 + (off1 - 96)] = c1;
}

extern "C" void kernel_launch(void* const* d_in, const int* in_sizes, int n_in,
                              void* d_out, int out_size, void* d_ws, size_t ws_size,
                              hipStream_t stream) {
    const float* cache       = (const float*)d_in[0];
    const float* refdirs     = (const float*)d_in[1];
    const float* normal      = (const float*)d_in[2];
    const float* samp_rays   = (const float*)d_in[3];
    const float* samp_mipval = (const float*)d_in[4];
    float* out = (float*)d_out;

    const int B = in_sizes[1] / 3;  // 65536

    fused_kernel<<<B / 4, 256, 0, stream>>>(cache, refdirs, normal,
                                            (const float4*)samp_rays,
                                            (const float4*)samp_mipval,
                                            out, B);
}

// Round 12
// 232.046 us; speedup vs baseline: 1.0545x; 1.0545x over previous
//
#include <hip/hip_runtime.h>

#define NCACHE 384

__device__ __forceinline__ unsigned int sortable_bits(float f) {
    unsigned int u = __float_as_uint(f);
    return (u & 0x80000000u) ? ~u : (u | 0x80000000u);
}

// ---- rank-loop asm bodies ----------------------------------------------
// All-VALU, carries via vcc + sgpr-pair (no SALU ops, no VALU->SALU->VALU
// hazards). Each JMIX handles one j-value vs the lane's 4 m-keys, including
// the stable-tie term for the own chunk via v_bfe(M, jo) (jo = j within the
// own 32-block; tie iff v_j == v_m and jo < l5, and bit jo of M=(1<<l5)-1
// is exactly (jo < l5)).

#define JMIX(Q, JOS, O0, O1, O2, O3, KN, RN)                        \
    "v_cmp_" O0 "_u32 vcc, " Q ", %[k0]\n\t"                        \
    "v_cmp_" O1 "_u32 %[sc], " Q ", %[k1]\n\t"                      \
    "v_addc_co_u32 %[r0], vcc, 0, %[r0], vcc\n\t"                   \
    "v_addc_co_u32 %[r1], %[sc], 0, %[r1], %[sc]\n\t"               \
    "v_cmp_" O2 "_u32 vcc, " Q ", %[k2]\n\t"                        \
    "v_cmp_" O3 "_u32 %[sc], " Q ", %[k3]\n\t"                      \
    "v_addc_co_u32 %[r2], vcc, 0, %[r2], vcc\n\t"                   \
    "v_addc_co_u32 %[r3], %[sc], 0, %[r3], %[sc]\n\t"               \
    "v_cmp_eq_u32 vcc, " Q ", %[" KN "]\n\t"                        \
    "v_bfe_u32 %[t], %[M], " JOS ", 1\n\t"                          \
    "v_cndmask_b32 %[t], 0, %[t], vcc\n\t"                          \
    "v_add_u32 %[" RN "], %[t], %[" RN "]\n\t"

#define ITER_MIX(QV, J0, J1, J2, J3, O0, O1, O2, O3, KN, RN)        \
    do {                                                            \
        asm(JMIX("%[a]", J0, O0, O1, O2, O3, KN, RN)                \
            JMIX("%[b]", J1, O0, O1, O2, O3, KN, RN)                \
            JMIX("%[c]", J2, O0, O1, O2, O3, KN, RN)                \
            JMIX("%[d]", J3, O0, O1, O2, O3, KN, RN)                \
            : [r0]"+v"(r0), [r1]"+v"(r1), [r2]"+v"(r2), [r3]"+v"(r3), \
              [t]"=&v"(t), [sc]"=&s"(sc)                            \
            : [a]"v"(QV.x), [b]"v"(QV.y), [c]"v"(QV.z), [d]"v"(QV.w), \
              [k0]"v"(vk0), [k1]"v"(vk1), [k2]"v"(vk2), [k3]"v"(vk3), \
              [M]"v"(Mmask)                                         \
            : "vcc");                                               \
    } while (0)

#define OWN8(KB, O0, O1, O2, O3, KN, RN)                                            \
    { uint4 q = vq[(KB)*8 + 0]; ITER_MIX(q, "0","1","2","3",     O0,O1,O2,O3,KN,RN); } \
    { uint4 q = vq[(KB)*8 + 1]; ITER_MIX(q, "4","5","6","7",     O0,O1,O2,O3,KN,RN); } \
    { uint4 q = vq[(KB)*8 + 2]; ITER_MIX(q, "8","9","10","11",   O0,O1,O2,O3,KN,RN); } \
    { uint4 q = vq[(KB)*8 + 3]; ITER_MIX(q, "12","13","14","15", O0,O1,O2,O3,KN,RN); } \
    { uint4 q = vq[(KB)*8 + 4]; ITER_MIX(q, "16","17","18","19", O0,O1,O2,O3,KN,RN); } \
    { uint4 q = vq[(KB)*8 + 5]; ITER_MIX(q, "20","21","22","23", O0,O1,O2,O3,KN,RN); } \
    { uint4 q = vq[(KB)*8 + 6]; ITER_MIX(q, "24","25","26","27", O0,O1,O2,O3,KN,RN); } \
    { uint4 q = vq[(KB)*8 + 7]; ITER_MIX(q, "28","29","30","31", O0,O1,O2,O3,KN,RN); }

#define JLT(Q)                                                      \
    "v_cmp_lt_u32 vcc, " Q ", %[k0]\n\t"                            \
    "v_cmp_lt_u32 %[sc], " Q ", %[k1]\n\t"                          \
    "v_addc_co_u32 %[r0], vcc, 0, %[r0], vcc\n\t"                   \
    "v_addc_co_u32 %[r1], %[sc], 0, %[r1], %[sc]\n\t"               \
    "v_cmp_lt_u32 vcc, " Q ", %[k2]\n\t"                            \
    "v_cmp_lt_u32 %[sc], " Q ", %[k3]\n\t"                          \
    "v_addc_co_u32 %[r2], vcc, 0, %[r2], vcc\n\t"                   \
    "v_addc_co_u32 %[r3], %[sc], 0, %[r3], %[sc]\n\t"

// 256 threads = 4 waves; each HALF-WAVE handles one b (8 b per block).
// Lane (wave w, half h, l5=lane&31) owns m-keys m = c*32+l5, c=0..3, of
// b = blockIdx.x*8 + w*2 + h. Stable rank via per-chunk lt/le/own decomposition.
__global__ __launch_bounds__(256, 8) void fused_kernel(
    const float*  __restrict__ cache,        // (384,5)
    const float*  __restrict__ refdirs,      // (B,3)
    const float*  __restrict__ normal,       // (B,3)
    const float4* __restrict__ samp_rays4,   // B*96 float4
    const float4* __restrict__ samp_mip4,    // B*32 float4
    float* __restrict__ out, int B)
{
#pragma clang fp contract(off)
    __shared__ __align__(16) float4 scache[NCACHE];          // dir.xyz, mip
    __shared__ __align__(16) unsigned int vals[8][NCACHE];   // per-b sortable words
    __shared__ unsigned int bitmap[8][12];

    const int tid  = threadIdx.x;
    const int wave = tid >> 6;
    const int lane = tid & 63;
    const int h    = lane >> 5;
    const int l5   = lane & 31;
    const int vidx = wave * 2 + h;
    const int myb  = blockIdx.x * 8 + vidx;

    // Early-issue pass-through copy loads (latency hidden under rank loop).
    // 1024 float4 items per block: item i -> bb = base + (i>>7), off = i&127.
    const int bbase = blockIdx.x * 8;
    const int ia = tid, ib = tid + 256, ic = tid + 512, id = tid + 768;
    const int ba = bbase + (ia >> 7), oa = ia & 127;
    const int bbb = bbase + (ib >> 7), ob = ib & 127;
    const int bc = bbase + (ic >> 7), oc = ic & 127;
    const int bd = bbase + (id >> 7), od = id & 127;
    const float4 ca = (oa < 96) ? samp_rays4[(size_t)ba * 96 + oa]
                                : samp_mip4[(size_t)ba * 32 + (oa - 96)];
    const float4 cb = (ob < 96) ? samp_rays4[(size_t)bbb * 96 + ob]
                                : samp_mip4[(size_t)bbb * 32 + (ob - 96)];
    const float4 cc = (oc < 96) ? samp_rays4[(size_t)bc * 96 + oc]
                                : samp_mip4[(size_t)bc * 32 + (oc - 96)];
    const float4 cd = (od < 96) ? samp_rays4[(size_t)bd * 96 + od]
                                : samp_mip4[(size_t)bd * 32 + (od - 96)];

    // Stage cache into LDS as float4 (cooperative, once per block)
    for (int m = tid; m < NCACHE; m += 256) {
        scache[m] = make_float4(cache[m * 5 + 0], cache[m * 5 + 1],
                                cache[m * 5 + 2], cache[m * 5 + 3]);
    }
    if (tid < 96) (&bitmap[0][0])[tid] = 0u;

    const float nx = normal[myb * 3 + 0], ny = normal[myb * 3 + 1], nz = normal[myb * 3 + 2];
    const float rx = refdirs[myb * 3 + 0], ry = refdirs[myb * 3 + 1], rz = refdirs[myb * 3 + 2];

    __syncthreads();

    // Scores for this half-wave's b: m = c*32 + l5, c = 0..11 (384 total).
    // FMA left-chains (bit-exact vs reference); -0.0 canonicalized to +0.0.
    unsigned int vk0 = 0, vk1 = 0, vk2 = 0, vk3 = 0;
#pragma unroll
    for (int c = 0; c < 12; ++c) {
        const int m = c * 32 + l5;
        const float4 d = scache[m];
        float hemi = __builtin_fmaf(nz, d.z, __builtin_fmaf(ny, d.y, nx * d.x));
        float sim  = __builtin_fmaf(rz, d.z, __builtin_fmaf(ry, d.y, rx * d.x));
        float val  = (hemi > 0.0f) ? -sim : 0.0f;
        val = val + 0.0f;
        const unsigned int sv = sortable_bits(val);
        vals[vidx][m] = sv;
        if (c == 0) vk0 = sv;
        if (c == 1) vk1 = sv;
        if (c == 2) vk2 = sv;
        if (c == 3) vk3 = sv;
    }
    // vals[vidx] written and read by the SAME half-wave; DS ops of one wave
    // complete in order -> no barrier (proven R8-R11).

    const uint4* vq = (const uint4*)&vals[vidx][0];
    const unsigned int Mmask = (1u << l5) - 1u;
    unsigned int r0 = 0, r1 = 0, r2 = 0, r3 = 0;
    unsigned int t;
    unsigned long long sc;

    // j-blocks 0..3 contain the m-chunks: mixed lt/le + own-chunk tie.
    OWN8(0, "lt", "le", "le", "le", "k0", "r0");
    OWN8(1, "lt", "lt", "le", "le", "k1", "r1");
    OWN8(2, "lt", "lt", "lt", "le", "k2", "r2");
    OWN8(3, "lt", "lt", "lt", "lt", "k3", "r3");

    // j-blocks 4..11 (j >= 128): strictly above all m-keys -> lt only.
#pragma unroll 8
    for (int i = 32; i < 96; ++i) {
        const uint4 q = vq[i];
        asm(JLT("%[a]") JLT("%[b]") JLT("%[c]") JLT("%[d]")
            : [r0]"+v"(r0), [r1]"+v"(r1), [r2]"+v"(r2), [r3]"+v"(r3),
              [sc]"=&s"(sc)
            : [a]"v"(q.x), [b]"v"(q.y), [c]"v"(q.z), [d]"v"(q.w),
              [k0]"v"(vk0), [k1]"v"(vk1), [k2]"v"(vk2), [k3]"v"(vk3)
            : "vcc");
    }

    // Ranks are distinct in [0,384). Output slot = #{selected ranks < r}.
    atomicOr(&bitmap[vidx][r0 >> 5], 1u << (r0 & 31));
    atomicOr(&bitmap[vidx][r1 >> 5], 1u << (r1 & 31));
    atomicOr(&bitmap[vidx][r2 >> 5], 1u << (r2 & 31));
    atomicOr(&bitmap[vidx][r3 >> 5], 1u << (r3 & 31));

    float* out_rays = out;
    float* out_mip  = out + (size_t)B * 768;

#pragma unroll
    for (int c = 0; c < 4; ++c) {
        const unsigned int r = (c == 0) ? r0 : (c == 1) ? r1 : (c == 2) ? r2 : r3;
        const int wi = (int)(r >> 5);
        int s = __popc(bitmap[vidx][wi] & ((1u << (r & 31)) - 1u));
        for (int w = 0; w < wi; ++w) s += __popc(bitmap[vidx][w]);
        const float4 g = scache[r];
        const size_t rb = (size_t)myb * 768 + 384 + (size_t)s * 3;
        out_rays[rb + 0] = g.x;
        out_rays[rb + 1] = g.y;
        out_rays[rb + 2] = g.z;
        out_mip[(size_t)myb * 256 + 128 + s] = g.w;
    }

    // Pass-through copy stores (loads issued at kernel entry).
    float4* out4     = (float4*)out;
    float4* out_mip4 = (float4*)(out + (size_t)B * 768);
    if (oa < 96) out4[(size_t)ba * 192 + oa] = ca;
    else         out_mip4[(size_t)ba * 64 + (oa - 96)] = ca;
    if (ob < 96) out4[(size_t)bbb * 192 + ob] = cb;
    else         out_mip4[(size_t)bbb * 64 + (ob - 96)] = cb;
    if (oc < 96) out4[(size_t)bc * 192 + oc] = cc;
    else         out_mip4[(size_t)bc * 64 + (oc - 96)] = cc;
    if (od < 96) out4[(size_t)bd * 192 + od] = cd;
    else         out_mip4[(size_t)bd * 64 + (od - 96)] = cd;
}

extern "C" void kernel_launch(void* const* d_in, const int* in_sizes, int n_in,
                              void* d_out, int out_size, void* d_ws, size_t ws_size,
                              hipStream_t stream) {
    const float* cache       = (const float*)d_in[0];
    const float* refdirs     = (const float*)d_in[1];
    const float* normal      = (const float*)d_in[2];
    const float* samp_rays   = (const float*)d_in[3];
    const float* samp_mipval = (const float*)d_in[4];
    float* out = (float*)d_out;

    const int B = in_sizes[1] / 3;  // 65536

    fused_kernel<<<B / 8, 256, 0, stream>>>(cache, refdirs, normal,
                                            (const float4*)samp_rays,
                                            (const float4*)samp_mipval,
                                            out, B);
}

// Round 13
// 231.947 us; speedup vs baseline: 1.0549x; 1.0004x over previous
//
#include <hip/hip_runtime.h>

#define NCACHE 384

__device__ __forceinline__ unsigned int sortable_bits(float f) {
    unsigned int u = __float_as_uint(f);
    return (u & 0x80000000u) ? ~u : (u | 0x80000000u);
}

// ---- rank-loop asm bodies, 4 independent carry chains -------------------
// Producer->consumer distance = 4 instructions (cmp writes vcc/sA/sB/sC,
// addc reads them 4 slots later) to hide the VALU-writes-carry ->
// VALU-reads-carry pipeline hazard that stalled R4-R12 (~2.3x static).

// One j vs 4 keys, all-lt (j strictly above all keys).
#define JLT4(Q)                                                     \
    "v_cmp_lt_u32 vcc, " Q ", %[k0]\n\t"                            \
    "v_cmp_lt_u32 %[sA], " Q ", %[k1]\n\t"                          \
    "v_cmp_lt_u32 %[sB], " Q ", %[k2]\n\t"                          \
    "v_cmp_lt_u32 %[sC], " Q ", %[k3]\n\t"                          \
    "v_addc_co_u32 %[r0], vcc, 0, %[r0], vcc\n\t"                   \
    "v_addc_co_u32 %[r1], %[sA], 0, %[r1], %[sA]\n\t"               \
    "v_addc_co_u32 %[r2], %[sB], 0, %[r2], %[sB]\n\t"               \
    "v_addc_co_u32 %[r3], %[sC], 0, %[r3], %[sC]\n\t"

// One j vs 4 keys in the j-block containing key KO (own chunk):
// own key via vcc chain (lt + tie), other three via sA/sB/sC (lt or le).
#define JOWN(Q, JOS, KO, RO, O1, K1, R1, O2, K2, R2, O3, K3, R3)    \
    "v_cmp_lt_u32 vcc, " Q ", %[" KO "]\n\t"                        \
    "v_cmp_" O1 "_u32 %[sA], " Q ", %[" K1 "]\n\t"                  \
    "v_cmp_" O2 "_u32 %[sB], " Q ", %[" K2 "]\n\t"                  \
    "v_cmp_" O3 "_u32 %[sC], " Q ", %[" K3 "]\n\t"                  \
    "v_addc_co_u32 %[" RO "], vcc, 0, %[" RO "], vcc\n\t"           \
    "v_addc_co_u32 %[" R1 "], %[sA], 0, %[" R1 "], %[sA]\n\t"       \
    "v_addc_co_u32 %[" R2 "], %[sB], 0, %[" R2 "], %[sB]\n\t"       \
    "v_addc_co_u32 %[" R3 "], %[sC], 0, %[" R3 "], %[sC]\n\t"       \
    "v_cmp_eq_u32 vcc, " Q ", %[" KO "]\n\t"                        \
    "v_bfe_u32 %[t], %[M], " JOS ", 1\n\t"                          \
    "v_cndmask_b32 %[t], 0, %[t], vcc\n\t"                          \
    "v_add_u32 %[" RO "], %[t], %[" RO "]\n\t"

#define ITER_OWN(QV, J0, J1, J2, J3, KO, RO, O1, K1, R1, O2, K2, R2, O3, K3, R3) \
    do {                                                            \
        asm(JOWN("%[a]", J0, KO, RO, O1, K1, R1, O2, K2, R2, O3, K3, R3) \
            JOWN("%[b]", J1, KO, RO, O1, K1, R1, O2, K2, R2, O3, K3, R3) \
            JOWN("%[c]", J2, KO, RO, O1, K1, R1, O2, K2, R2, O3, K3, R3) \
            JOWN("%[d]", J3, KO, RO, O1, K1, R1, O2, K2, R2, O3, K3, R3) \
            : [r0]"+v"(r0), [r1]"+v"(r1), [r2]"+v"(r2), [r3]"+v"(r3), \
              [t]"=&v"(t), [sA]"=&s"(scA), [sB]"=&s"(scB), [sC]"=&s"(scC) \
            : [a]"v"(QV.x), [b]"v"(QV.y), [c]"v"(QV.z), [d]"v"(QV.w), \
              [k0]"v"(vk0), [k1]"v"(vk1), [k2]"v"(vk2), [k3]"v"(vk3), \
              [M]"v"(Mmask)                                         \
            : "vcc");                                               \
    } while (0)

#define OWN8(KB, KO, RO, O1, K1, R1, O2, K2, R2, O3, K3, R3)                                  \
    { uint4 q = vq[(KB)*8 + 0]; ITER_OWN(q, "0","1","2","3",     KO,RO,O1,K1,R1,O2,K2,R2,O3,K3,R3); } \
    { uint4 q = vq[(KB)*8 + 1]; ITER_OWN(q, "4","5","6","7",     KO,RO,O1,K1,R1,O2,K2,R2,O3,K3,R3); } \
    { uint4 q = vq[(KB)*8 + 2]; ITER_OWN(q, "8","9","10","11",   KO,RO,O1,K1,R1,O2,K2,R2,O3,K3,R3); } \
    { uint4 q = vq[(KB)*8 + 3]; ITER_OWN(q, "12","13","14","15", KO,RO,O1,K1,R1,O2,K2,R2,O3,K3,R3); } \
    { uint4 q = vq[(KB)*8 + 4]; ITER_OWN(q, "16","17","18","19", KO,RO,O1,K1,R1,O2,K2,R2,O3,K3,R3); } \
    { uint4 q = vq[(KB)*8 + 5]; ITER_OWN(q, "20","21","22","23", KO,RO,O1,K1,R1,O2,K2,R2,O3,K3,R3); } \
    { uint4 q = vq[(KB)*8 + 6]; ITER_OWN(q, "24","25","26","27", KO,RO,O1,K1,R1,O2,K2,R2,O3,K3,R3); } \
    { uint4 q = vq[(KB)*8 + 7]; ITER_OWN(q, "28","29","30","31", KO,RO,O1,K1,R1,O2,K2,R2,O3,K3,R3); }

// 256 threads = 4 waves; each HALF-WAVE handles one b (8 b per block).
// Lane (wave w, half h, l5=lane&31) owns m-keys m = c*32+l5, c=0..3, of
// b = blockIdx.x*8 + w*2 + h. Stable rank via per-chunk lt/le/own decomposition.
__global__ __launch_bounds__(256, 8) void fused_kernel(
    const float*  __restrict__ cache,        // (384,5)
    const float*  __restrict__ refdirs,      // (B,3)
    const float*  __restrict__ normal,       // (B,3)
    const float4* __restrict__ samp_rays4,   // B*96 float4
    const float4* __restrict__ samp_mip4,    // B*32 float4
    float* __restrict__ out, int B)
{
#pragma clang fp contract(off)
    __shared__ __align__(16) float4 scache[NCACHE];          // dir.xyz, mip
    __shared__ __align__(16) unsigned int vals[8][NCACHE];   // per-b sortable words
    __shared__ unsigned int bitmap[8][12];

    const int tid  = threadIdx.x;
    const int wave = tid >> 6;
    const int lane = tid & 63;
    const int h    = lane >> 5;
    const int l5   = lane & 31;
    const int vidx = wave * 2 + h;
    const int myb  = blockIdx.x * 8 + vidx;

    // Early-issue pass-through copy loads (latency hidden under rank loop).
    const int bbase = blockIdx.x * 8;
    const int ia = tid, ib = tid + 256, ic = tid + 512, id = tid + 768;
    const int ba = bbase + (ia >> 7), oa = ia & 127;
    const int bbb = bbase + (ib >> 7), ob = ib & 127;
    const int bc = bbase + (ic >> 7), oc = ic & 127;
    const int bd = bbase + (id >> 7), od = id & 127;
    const float4 ca = (oa < 96) ? samp_rays4[(size_t)ba * 96 + oa]
                                : samp_mip4[(size_t)ba * 32 + (oa - 96)];
    const float4 cb = (ob < 96) ? samp_rays4[(size_t)bbb * 96 + ob]
                                : samp_mip4[(size_t)bbb * 32 + (ob - 96)];
    const float4 cc = (oc < 96) ? samp_rays4[(size_t)bc * 96 + oc]
                                : samp_mip4[(size_t)bc * 32 + (oc - 96)];
    const float4 cd = (od < 96) ? samp_rays4[(size_t)bd * 96 + od]
                                : samp_mip4[(size_t)bd * 32 + (od - 96)];

    // Stage cache into LDS as float4 (cooperative, once per block)
    for (int m = tid; m < NCACHE; m += 256) {
        scache[m] = make_float4(cache[m * 5 + 0], cache[m * 5 + 1],
                                cache[m * 5 + 2], cache[m * 5 + 3]);
    }
    if (tid < 96) (&bitmap[0][0])[tid] = 0u;

    const float nx = normal[myb * 3 + 0], ny = normal[myb * 3 + 1], nz = normal[myb * 3 + 2];
    const float rx = refdirs[myb * 3 + 0], ry = refdirs[myb * 3 + 1], rz = refdirs[myb * 3 + 2];

    __syncthreads();

    // Scores for this half-wave's b: m = c*32 + l5, c = 0..11 (384 total).
    // FMA left-chains (bit-exact vs reference); -0.0 canonicalized to +0.0.
    unsigned int vk0 = 0, vk1 = 0, vk2 = 0, vk3 = 0;
#pragma unroll
    for (int c = 0; c < 12; ++c) {
        const int m = c * 32 + l5;
        const float4 d = scache[m];
        float hemi = __builtin_fmaf(nz, d.z, __builtin_fmaf(ny, d.y, nx * d.x));
        float sim  = __builtin_fmaf(rz, d.z, __builtin_fmaf(ry, d.y, rx * d.x));
        float val  = (hemi > 0.0f) ? -sim : 0.0f;
        val = val + 0.0f;
        const unsigned int sv = sortable_bits(val);
        vals[vidx][m] = sv;
        if (c == 0) vk0 = sv;
        if (c == 1) vk1 = sv;
        if (c == 2) vk2 = sv;
        if (c == 3) vk3 = sv;
    }
    // vals[vidx] written and read by the SAME half-wave; DS ops of one wave
    // complete in order -> no barrier (proven R8-R12).

    const uint4* vq = (const uint4*)&vals[vidx][0];
    const unsigned int Mmask = (1u << l5) - 1u;
    unsigned int r0 = 0, r1 = 0, r2 = 0, r3 = 0;
    unsigned int t;
    unsigned long long scA, scB, scC;

    // j-blocks 0..3 contain the m-chunks: own-key tie + lt/le decomposition.
    // Key c vs j-block bc: bc<c -> le, bc>c -> lt, bc==c -> own (lt + tie).
    OWN8(0, "k0", "r0", "le", "k1", "r1", "le", "k2", "r2", "le", "k3", "r3");
    OWN8(1, "k1", "r1", "lt", "k0", "r0", "le", "k2", "r2", "le", "k3", "r3");
    OWN8(2, "k2", "r2", "lt", "k0", "r0", "lt", "k1", "r1", "le", "k3", "r3");
    OWN8(3, "k3", "r3", "lt", "k0", "r0", "lt", "k1", "r1", "lt", "k2", "r2");

    // j-blocks 4..11 (j >= 128): strictly above all m-keys -> lt only.
#pragma unroll 8
    for (int i = 32; i < 96; ++i) {
        const uint4 q = vq[i];
        asm(JLT4("%[a]") JLT4("%[b]") JLT4("%[c]") JLT4("%[d]")
            : [r0]"+v"(r0), [r1]"+v"(r1), [r2]"+v"(r2), [r3]"+v"(r3),
              [sA]"=&s"(scA), [sB]"=&s"(scB), [sC]"=&s"(scC)
            : [a]"v"(q.x), [b]"v"(q.y), [c]"v"(q.z), [d]"v"(q.w),
              [k0]"v"(vk0), [k1]"v"(vk1), [k2]"v"(vk2), [k3]"v"(vk3)
            : "vcc");
    }

    // Ranks are distinct in [0,384). Output slot = #{selected ranks < r}.
    atomicOr(&bitmap[vidx][r0 >> 5], 1u << (r0 & 31));
    atomicOr(&bitmap[vidx][r1 >> 5], 1u << (r1 & 31));
    atomicOr(&bitmap[vidx][r2 >> 5], 1u << (r2 & 31));
    atomicOr(&bitmap[vidx][r3 >> 5], 1u << (r3 & 31));

    float* out_rays = out;
    float* out_mip  = out + (size_t)B * 768;

#pragma unroll
    for (int c = 0; c < 4; ++c) {
        const unsigned int r = (c == 0) ? r0 : (c == 1) ? r1 : (c == 2) ? r2 : r3;
        const int wi = (int)(r >> 5);
        int s = __popc(bitmap[vidx][wi] & ((1u << (r & 31)) - 1u));
        for (int w = 0; w < wi; ++w) s += __popc(bitmap[vidx][w]);
        const float4 g = scache[r];
        const size_t rb = (size_t)myb * 768 + 384 + (size_t)s * 3;
        out_rays[rb + 0] = g.x;
        out_rays[rb + 1] = g.y;
        out_rays[rb + 2] = g.z;
        out_mip[(size_t)myb * 256 + 128 + s] = g.w;
    }

    // Pass-through copy stores (loads issued at kernel entry).
    float4* out4     = (float4*)out;
    float4* out_mip4 = (float4*)(out + (size_t)B * 768);
    if (oa < 96) out4[(size_t)ba * 192 + oa] = ca;
    else         out_mip4[(size_t)ba * 64 + (oa - 96)] = ca;
    if (ob < 96) out4[(size_t)bbb * 192 + ob] = cb;
    else         out_mip4[(size_t)bbb * 64 + (ob - 96)] = cb;
    if (oc < 96) out4[(size_t)bc * 192 + oc] = cc;
    else         out_mip4[(size_t)bc * 64 + (oc - 96)] = cc;
    if (od < 96) out4[(size_t)bd * 192 + od] = cd;
    else         out_mip4[(size_t)bd * 64 + (od - 96)] = cd;
}

extern "C" void kernel_launch(void* const* d_in, const int* in_sizes, int n_in,
                              void* d_out, int out_size, void* d_ws, size_t ws_size,
                              hipStream_t stream) {
    const float* cache       = (const float*)d_in[0];
    const float* refdirs     = (const float*)d_in[1];
    const float* normal      = (const float*)d_in[2];
    const float* samp_rays   = (const float*)d_in[3];
    const float* samp_mipval = (const float*)d_in[4];
    float* out = (float*)d_out;

    const int B = in_sizes[1] / 3;  // 65536

    fused_kernel<<<B / 8, 256, 0, stream>>>(cache, refdirs, normal,
                                            (const float4*)samp_rays,
                                            (const float4*)samp_mipval,
                                            out, B);
}